// Round 4
// baseline (35.116 us; speedup 1.0000x reference)
//
#include <hip/hip_runtime.h>
#include <hip/hip_bf16.h>

// ComplexLayerScale: out_real = x_r*g_r - x_i*g_i  (harness materializes the
// real part only: out_size == B*T*D, float32). Fallback complex path kept.
//
// R1: 34.35us grid-stride. R3: 33.0us flat launch, nt stores (FETCH unchanged
// -> nt neutral). Aggregate CU-side traffic 192MB/33us = 5.82 TB/s = 92.5% of
// the 6.29 TB/s copy ceiling. R4: ILP-2 probe — each thread handles 2
// consecutive f32x4s (32B), both loads issued before use; 8192 blocks.
// If latency/ramp-limited -> ~30.5us; if BW-saturated -> unchanged.

typedef float f32x4 __attribute__((ext_vector_type(4)));

__global__ void __launch_bounds__(256)
cls_real_kernel(const f32x4* __restrict__ xr, const f32x4* __restrict__ xi,
                const f32x4* __restrict__ gr4, const f32x4* __restrict__ gi4,
                f32x4* __restrict__ out) {
    long tid = (long)blockIdx.x * blockDim.x + threadIdx.x;
    long i0 = tid * 2;          // two consecutive f32x4s per thread
    // channel of f32x4 #k is (i0+k) % 128 in f32x4 units
    int c0 = (int)(i0 & 127);
    int c1 = (int)((i0 + 1) & 127);
    // issue all independent loads first (ILP)
    f32x4 a0 = xr[i0];
    f32x4 a1 = xr[i0 + 1];
    f32x4 b0 = xi[i0];
    f32x4 b1 = xi[i0 + 1];
    f32x4 gr0 = gr4[c0];
    f32x4 gr1 = gr4[c1];
    f32x4 gi0 = gi4[c0];
    f32x4 gi1 = gi4[c1];
    f32x4 o0 = a0 * gr0 - b0 * gi0;
    f32x4 o1 = a1 * gr1 - b1 * gi1;
    __builtin_nontemporal_store(o0, &out[i0]);
    __builtin_nontemporal_store(o1, &out[i0 + 1]);
}

__global__ void __launch_bounds__(256)
cls_complex_kernel(const f32x4* __restrict__ xr, const f32x4* __restrict__ xi,
                   const f32x4* __restrict__ gr4, const f32x4* __restrict__ gi4,
                   f32x4* __restrict__ out) {
    long tid = (long)blockIdx.x * blockDim.x + threadIdx.x;
    int c4 = (int)(tid & 127);
    f32x4 gr = gr4[c4];
    f32x4 gi = gi4[c4];
    f32x4 a = xr[tid];
    f32x4 b = xi[tid];
    f32x4 re = a * gr - b * gi;
    f32x4 im = a * gi + b * gr;
    f32x4 o0 = {re.x, im.x, re.y, im.y};
    f32x4 o1 = {re.z, im.z, re.w, im.w};
    __builtin_nontemporal_store(o0, &out[2 * tid]);
    __builtin_nontemporal_store(o1, &out[2 * tid + 1]);
}

extern "C" void kernel_launch(void* const* d_in, const int* in_sizes, int n_in,
                              void* d_out, int out_size, void* d_ws, size_t ws_size,
                              hipStream_t stream) {
    const f32x4* xr  = (const f32x4*)d_in[0];
    const f32x4* xi  = (const f32x4*)d_in[1];
    const f32x4* gr4 = (const f32x4*)d_in[2];
    const f32x4* gi4 = (const f32x4*)d_in[3];
    f32x4* out = (f32x4*)d_out;

    const long N  = (long)in_sizes[0];   // B*T*D = 16,777,216
    const long n4 = N / 4;               // 4,194,304 f32x4s

    const int block = 256;

    if ((long)out_size == N) {
        const int grid = (int)(n4 / (block * 2)); // 8192 blocks, 2 f32x4/thread
        cls_real_kernel<<<grid, block, 0, stream>>>(xr, xi, gr4, gi4, out);
    } else {
        const int grid = (int)(n4 / block);
        cls_complex_kernel<<<grid, block, 0, stream>>>(xr, xi, gr4, gi4, out);
    }
}

// Round 5
// 34.360 us; speedup vs baseline: 1.0220x; 1.0220x over previous
//
#include <hip/hip_runtime.h>
#include <hip/hip_bf16.h>

// ComplexLayerScale: out_real = x_r*g_r - x_i*g_i  (harness materializes the
// real part only: out_size == B*T*D, float32). Fallback complex path kept.
//
// R1: 34.35us grid-stride. R3: 33.0us flat, 5.82 TB/s aggregate (92.5% of
// 6.29 TB/s copy ceiling). R4 FAILED (35.1us): consecutive-pair ILP-2 broke
// store coalescing (WRITE_SIZE 65.5->74MB, 32B-stride lanes).
// R5: clean ILP-2 — thread t handles f32x4 t and t+n4/2 (split halves).
// Every memory instruction lane-consecutive; n4/2 % 128 == 0 so both halves
// share one gamma channel. Decides latency-limited (~30.5us) vs BW-saturated
// (~33us).

typedef float f32x4 __attribute__((ext_vector_type(4)));

__global__ void __launch_bounds__(256)
cls_real_kernel(const f32x4* __restrict__ xr, const f32x4* __restrict__ xi,
                const f32x4* __restrict__ gr4, const f32x4* __restrict__ gi4,
                f32x4* __restrict__ out, long half) {
    long tid = (long)blockIdx.x * blockDim.x + threadIdx.x;
    long i0 = tid;
    long i1 = tid + half;       // half % 128 == 0 -> same gamma channel
    int c4 = (int)(tid & 127);
    // issue all independent loads first (ILP), all lane-consecutive
    f32x4 a0 = xr[i0];
    f32x4 a1 = xr[i1];
    f32x4 b0 = xi[i0];
    f32x4 b1 = xi[i1];
    f32x4 gr = gr4[c4];
    f32x4 gi = gi4[c4];
    f32x4 o0 = a0 * gr - b0 * gi;
    f32x4 o1 = a1 * gr - b1 * gi;
    __builtin_nontemporal_store(o0, &out[i0]);
    __builtin_nontemporal_store(o1, &out[i1]);
}

__global__ void __launch_bounds__(256)
cls_complex_kernel(const f32x4* __restrict__ xr, const f32x4* __restrict__ xi,
                   const f32x4* __restrict__ gr4, const f32x4* __restrict__ gi4,
                   f32x4* __restrict__ out) {
    long tid = (long)blockIdx.x * blockDim.x + threadIdx.x;
    int c4 = (int)(tid & 127);
    f32x4 gr = gr4[c4];
    f32x4 gi = gi4[c4];
    f32x4 a = xr[tid];
    f32x4 b = xi[tid];
    f32x4 re = a * gr - b * gi;
    f32x4 im = a * gi + b * gr;
    f32x4 o0 = {re.x, im.x, re.y, im.y};
    f32x4 o1 = {re.z, im.z, re.w, im.w};
    __builtin_nontemporal_store(o0, &out[2 * tid]);
    __builtin_nontemporal_store(o1, &out[2 * tid + 1]);
}

extern "C" void kernel_launch(void* const* d_in, const int* in_sizes, int n_in,
                              void* d_out, int out_size, void* d_ws, size_t ws_size,
                              hipStream_t stream) {
    const f32x4* xr  = (const f32x4*)d_in[0];
    const f32x4* xi  = (const f32x4*)d_in[1];
    const f32x4* gr4 = (const f32x4*)d_in[2];
    const f32x4* gi4 = (const f32x4*)d_in[3];
    f32x4* out = (f32x4*)d_out;

    const long N  = (long)in_sizes[0];   // B*T*D = 16,777,216
    const long n4 = N / 4;               // 4,194,304 f32x4s
    const long half = n4 / 2;            // 2,097,152 (multiple of 128)

    const int block = 256;

    if ((long)out_size == N) {
        const int grid = (int)(half / block); // 8192 blocks, 2 f32x4/thread
        cls_real_kernel<<<grid, block, 0, stream>>>(xr, xi, gr4, gi4, out, half);
    } else {
        const int grid = (int)(n4 / block);
        cls_complex_kernel<<<grid, block, 0, stream>>>(xr, xi, gr4, gi4, out);
    }
}

// Round 6
// 33.782 us; speedup vs baseline: 1.0395x; 1.0171x over previous
//
#include <hip/hip_runtime.h>
#include <hip/hip_bf16.h>

// ComplexLayerScale: out_real = x_r*g_r - x_i*g_i  (harness materializes the
// real part only: out_size == B*T*D, float32). Fallback complex path kept.
//
// History: R1 grid-stride 34.35us. R3 flat+nt 33.0us (best) = 5.82 TB/s
// aggregate = 92.5% of 6.29 TB/s copy ceiling. R4 consecutive-ILP2 35.1us
// (broke store coalescing, WRITE 74MB). R5 split-half-ILP2 34.4us (coalescing
// fixed, no gain -> BW-saturated, not latency-limited).
// R6 = restore R3 (best). 192MB irreducible traffic / ~5.8 TB/s ~= 33us.
// This is the structural memory roofline.

typedef float f32x4 __attribute__((ext_vector_type(4)));

__global__ void __launch_bounds__(256)
cls_real_kernel(const f32x4* __restrict__ xr, const f32x4* __restrict__ xi,
                const f32x4* __restrict__ gr4, const f32x4* __restrict__ gi4,
                f32x4* __restrict__ out) {
    long tid = (long)blockIdx.x * blockDim.x + threadIdx.x;
    // element base = tid*4; channel = (tid*4) % 512; f32x4 gamma idx = tid % 128
    int c4 = (int)(tid & 127);
    f32x4 gr = gr4[c4];
    f32x4 gi = gi4[c4];
    f32x4 a = xr[tid];
    f32x4 b = xi[tid];
    f32x4 o = a * gr - b * gi;
    __builtin_nontemporal_store(o, &out[tid]);
}

__global__ void __launch_bounds__(256)
cls_complex_kernel(const f32x4* __restrict__ xr, const f32x4* __restrict__ xi,
                   const f32x4* __restrict__ gr4, const f32x4* __restrict__ gi4,
                   f32x4* __restrict__ out) {
    long tid = (long)blockIdx.x * blockDim.x + threadIdx.x;
    int c4 = (int)(tid & 127);
    f32x4 gr = gr4[c4];
    f32x4 gi = gi4[c4];
    f32x4 a = xr[tid];
    f32x4 b = xi[tid];
    f32x4 re = a * gr - b * gi;
    f32x4 im = a * gi + b * gr;
    f32x4 o0 = {re.x, im.x, re.y, im.y};
    f32x4 o1 = {re.z, im.z, re.w, im.w};
    __builtin_nontemporal_store(o0, &out[2 * tid]);
    __builtin_nontemporal_store(o1, &out[2 * tid + 1]);
}

extern "C" void kernel_launch(void* const* d_in, const int* in_sizes, int n_in,
                              void* d_out, int out_size, void* d_ws, size_t ws_size,
                              hipStream_t stream) {
    const f32x4* xr  = (const f32x4*)d_in[0];
    const f32x4* xi  = (const f32x4*)d_in[1];
    const f32x4* gr4 = (const f32x4*)d_in[2];
    const f32x4* gi4 = (const f32x4*)d_in[3];
    f32x4* out = (f32x4*)d_out;

    const long N  = (long)in_sizes[0];   // B*T*D = 16,777,216
    const long n4 = N / 4;               // 4,194,304 f32x4s

    const int block = 256;
    const int grid  = (int)(n4 / block); // 16384 blocks, one f32x4 per thread

    if ((long)out_size == N) {
        cls_real_kernel<<<grid, block, 0, stream>>>(xr, xi, gr4, gi4, out);
    } else {
        cls_complex_kernel<<<grid, block, 0, stream>>>(xr, xi, gr4, gi4, out);
    }
}